// Round 9
// baseline (162.902 us; speedup 1.0000x reference)
//
#include <hip/hip_runtime.h>

// Problem constants (fixed by the reference)
#define N_NODES   100000
#define N_EDGES   1600000
#define IN_CH     16
#define HID_CH    64
#define OUT_CH    128
#define N_GRAPHS  128

// Capacities. Expected: slots ~2.2K, list1 ~35K, list2 ~2K.
#define CAPS  4096
#define CAP1  65536
#define CAP2  16384

#define BM_WORDS ((N_NODES + 31) / 32)          // 3125 words = 12.5 KB bitmap

#define SCAN_BLOCKS 2048
#define SCAN_CHUNK  ((N_EDGES + SCAN_BLOCKS - 1) / SCAN_BLOCKS)   // 782 edges/block

// ---------------- kernels ----------------

__global__ void k_init(unsigned int* deg, int* map1, float* h1, float* out2,
                       int* cnt, unsigned int* cbm, unsigned int* mbm,
                       unsigned int* ndbm) {
    int i = blockIdx.x * blockDim.x + threadIdx.x;
    int st = gridDim.x * blockDim.x;
    for (int n = i; n < N_NODES; n += st) { deg[n] = 0u; map1[n] = -1; }
    for (int n = i; n < CAPS * HID_CH; n += st) h1[n] = 0.0f;
    for (int n = i; n < N_GRAPHS * OUT_CH; n += st) out2[n] = 0.0f;
    for (int n = i; n < BM_WORDS; n += st) { cbm[n] = 0u; mbm[n] = 0u; ndbm[n] = 0u; }
    if (i < 8) cnt[i] = 0;
}

// Mark central nodes: map1=-2, central bitmap, needed-deg bitmap.
__global__ void k_central(const int* __restrict__ ptr, int* map1,
                          unsigned int* cbm, unsigned int* ndbm) {
    int i = threadIdx.x;
    if (i < N_GRAPHS) {
        int c = ptr[i];
        map1[c] = -2;
        atomicOr(&cbm[c >> 5], 1u << (c & 31));
        atomicOr(&ndbm[c >> 5], 1u << (c & 31));
    }
}

// Scan 1: central-dst edge detection. NO degree counting. list2 via LDS buffer.
__global__ void __launch_bounds__(256) k_pass1(
        const int* __restrict__ src, const int* __restrict__ dst,
        const unsigned int* __restrict__ cbm,
        int* map1, int* list2, int* cnt) {
    __shared__ int lbuf[SCAN_CHUNK];
    __shared__ int lcnt, gbase;
    if (threadIdx.x == 0) lcnt = 0;
    __syncthreads();
    int e0 = blockIdx.x * SCAN_CHUNK;
    int e1 = min(e0 + SCAN_CHUNK, N_EDGES);
    for (int e = e0 + (int)threadIdx.x; e < e1; e += blockDim.x) {
        int d = dst[e];
        if ((cbm[d >> 5] >> (d & 31)) & 1u) {
            map1[src[e]] = -2;                  // benign same-value race
            int idx = atomicAdd(&lcnt, 1);      // LDS atomic
            lbuf[idx] = e;
        }
    }
    __syncthreads();
    if (threadIdx.x == 0) gbase = atomicAdd(&cnt[2], lcnt);
    __syncthreads();
    for (int t = threadIdx.x; t < lcnt; t += blockDim.x) {
        int gi = gbase + t;
        if (gi < CAP2) list2[gi] = lbuf[t];
    }
}

// Compact marked nodes -> slots (wave-aggregated counter); set marked bitmap
// and needed-deg bitmap.
__global__ void k_node(int* map1, int* slotnode, int* cnt,
                       unsigned int* mbm, unsigned int* ndbm) {
    int lane = threadIdx.x & 63;
    int i = blockIdx.x * blockDim.x + threadIdx.x;
    int st = gridDim.x * blockDim.x;
    for (int n = i; n < N_NODES; n += st) {
        bool need = (map1[n] == -2);
        unsigned long long mk = __ballot(need);
        if (mk) {
            int leader = __ffsll((long long)mk) - 1;
            int base = 0;
            if (lane == leader) base = atomicAdd(&cnt[0], __popcll(mk));
            base = __shfl(base, leader, 64);
            if (need) {
                int s = base + (int)__popcll(mk & ((1ull << lane) - 1));
                if (s < CAPS) { map1[n] = s; slotnode[s] = n; }
                else          { map1[n] = 0; }  // overflow: clamp, never fault
                atomicOr(&mbm[n >> 5], 1u << (n & 31));
                atomicOr(&ndbm[n >> 5], 1u << (n & 31));
            }
        }
    }
}

// Scan 2: edges whose dst is marked -> list1 (LDS buffer); mark src as
// needing a degree (atomicOr, ~35K total).
__global__ void __launch_bounds__(256) k_pass2(
        const int* __restrict__ src, const int* __restrict__ dst,
        const unsigned int* __restrict__ mbm,
        int* list1, int* cnt, unsigned int* ndbm) {
    __shared__ int lbuf[SCAN_CHUNK];
    __shared__ int lcnt, gbase;
    if (threadIdx.x == 0) lcnt = 0;
    __syncthreads();
    int e0 = blockIdx.x * SCAN_CHUNK;
    int e1 = min(e0 + SCAN_CHUNK, N_EDGES);
    for (int e = e0 + (int)threadIdx.x; e < e1; e += blockDim.x) {
        int d = dst[e];
        if ((mbm[d >> 5] >> (d & 31)) & 1u) {
            int s = src[e];
            atomicOr(&ndbm[s >> 5], 1u << (s & 31));
            int idx = atomicAdd(&lcnt, 1);      // LDS atomic
            lbuf[idx] = e;
        }
    }
    __syncthreads();
    if (threadIdx.x == 0) gbase = atomicAdd(&cnt[1], lcnt);
    __syncthreads();
    for (int t = threadIdx.x; t < lcnt; t += blockDim.x) {
        int gi = gbase + t;
        if (gi < CAP1) list1[gi] = lbuf[t];
    }
}

// Scan 3: degree counting ONLY for dst in the needed-deg set (~37% of edges).
__global__ void __launch_bounds__(256) k_pass3(
        const int* __restrict__ dst, const unsigned int* __restrict__ ndbm,
        unsigned int* deg) {
    int i = blockIdx.x * blockDim.x + threadIdx.x;
    int st = gridDim.x * blockDim.x;
    for (int e = i; e < N_EDGES; e += st) {
        int d = dst[e];
        if ((ndbm[d >> 5] >> (d & 31)) & 1u) atomicAdd(&deg[d], 1u);
    }
}

// dis = rsqrt(1 + deg)  (self-loop included; nodes outside needed set get
// garbage-free dis=rsqrt(1)=1, never used).
__global__ void k_dis(const unsigned int* __restrict__ deg, float* dis) {
    int i = blockIdx.x * blockDim.x + threadIdx.x;
    int st = gridDim.x * blockDim.x;
    for (int n = i; n < N_NODES; n += st) dis[n] = rsqrtf((float)(1u + deg[n]));
}

// Layer-1 edge scatter over list1: one wave per edge; lane = hidden channel.
__global__ void k_l1_edge(const int* __restrict__ src, const int* __restrict__ dst,
                          const float* __restrict__ x, const float* __restrict__ W1,
                          const float* __restrict__ dis, const int* __restrict__ map1,
                          const int* __restrict__ list1, const int* __restrict__ cnt,
                          float* h1) {
    __shared__ float w1s[IN_CH * HID_CH];
    for (int t = threadIdx.x; t < IN_CH * HID_CH; t += blockDim.x) w1s[t] = W1[t];
    __syncthreads();
    int lane = threadIdx.x & 63;
    int wid = blockIdx.x * (blockDim.x >> 6) + (threadIdx.x >> 6);
    int nw = gridDim.x * (blockDim.x >> 6);
    int n1 = min(cnt[1], CAP1);
    for (int w = wid; w < n1; w += nw) {
        int e = list1[w];
        int s = src[e];
        int d = dst[e];
        int slot = map1[d];                     // >= 0 by construction
        float norm = dis[s] * dis[d];
        float xv = (lane < IN_CH) ? x[s * IN_CH + lane] : 0.0f;
        float t = 0.0f;
#pragma unroll
        for (int c = 0; c < IN_CH; ++c)
            t += __shfl(xv, c, 64) * w1s[c * HID_CH + lane];
        atomicAdd(&h1[(size_t)slot * HID_CH + lane], t * norm);
    }
}

// Layer-1 self-loop + bias + ReLU (in place): one wave per slot.
__global__ void k_l1_self(const float* __restrict__ x, const float* __restrict__ W1,
                          const float* __restrict__ b1, const float* __restrict__ dis,
                          const int* __restrict__ slotnode, const int* __restrict__ cnt,
                          float* h1) {
    __shared__ float w1s[IN_CH * HID_CH];
    for (int t = threadIdx.x; t < IN_CH * HID_CH; t += blockDim.x) w1s[t] = W1[t];
    __syncthreads();
    int lane = threadIdx.x & 63;
    int wid = blockIdx.x * (blockDim.x >> 6) + (threadIdx.x >> 6);
    int nw = gridDim.x * (blockDim.x >> 6);
    int nS = min(cnt[0], CAPS);
    for (int sl = wid; sl < nS; sl += nw) {
        int n = slotnode[sl];
        float xv = (lane < IN_CH) ? x[n * IN_CH + lane] : 0.0f;
        float t = 0.0f;
#pragma unroll
        for (int c = 0; c < IN_CH; ++c)
            t += __shfl(xv, c, 64) * w1s[c * HID_CH + lane];
        float dn = dis[n];
        size_t off = (size_t)sl * HID_CH + lane;
        float v = h1[off] + t * dn * dn + b1[lane];
        h1[off] = v > 0.0f ? v : 0.0f;
    }
}

// Layer-2: listed central-dst edges (ballot row-resolution; duplicate rows
// each accumulate) + per-row self-loops appended as extra work items.
__global__ void k_l2(const int* __restrict__ src, const int* __restrict__ dst,
                     const int* __restrict__ ptr,
                     const float* __restrict__ h1, const float* __restrict__ W2,
                     const float* __restrict__ dis, const int* __restrict__ map1,
                     const int* __restrict__ list2, const int* __restrict__ cnt,
                     float* out2) {
    __shared__ int cent[128];
    if (threadIdx.x < 128) cent[threadIdx.x] = ptr[threadIdx.x];
    __syncthreads();
    int lane = threadIdx.x & 63;
    int c0 = cent[lane];
    int c1v = cent[lane + 64];
    int wid = blockIdx.x * (blockDim.x >> 6) + (threadIdx.x >> 6);
    int nw = gridDim.x * (blockDim.x >> 6);
    int n2 = min(cnt[2], CAP2);
    for (int w = wid; w < n2 + N_GRAPHS; w += nw) {
        int s, d, selfrow = -1;
        if (w < n2) {
            int e = list2[w];
            s = src[e]; d = dst[e];
        } else {
            selfrow = w - n2;
            s = cent[selfrow]; d = s;
        }
        int slot = map1[s]; if (slot < 0) slot = 0;   // always marked
        float norm = dis[s] * dis[d];
        const float* hrow = &h1[(size_t)slot * HID_CH];
        float a0 = 0.0f, a1 = 0.0f;
#pragma unroll 8
        for (int j = 0; j < HID_CH; ++j) {
            float hv = hrow[j];
            a0 += hv * W2[j * OUT_CH + lane];
            a1 += hv * W2[j * OUT_CH + lane + 64];
        }
        a0 *= norm; a1 *= norm;
        if (selfrow >= 0) {
            atomicAdd(&out2[selfrow * OUT_CH + lane], a0);
            atomicAdd(&out2[selfrow * OUT_CH + lane + 64], a1);
        } else {
            unsigned long long b0 = __ballot(c0 == d);
            unsigned long long b1 = __ballot(c1v == d);
            while (b0) {
                int r = __ffsll((long long)b0) - 1; b0 &= b0 - 1;
                atomicAdd(&out2[r * OUT_CH + lane], a0);
                atomicAdd(&out2[r * OUT_CH + lane + 64], a1);
            }
            while (b1) {
                int r = __ffsll((long long)b1) - 1 + 64; b1 &= b1 - 1;
                atomicAdd(&out2[r * OUT_CH + lane], a0);
                atomicAdd(&out2[r * OUT_CH + lane + 64], a1);
            }
        }
    }
}

// Final: add bias, write d_out (fp32).
__global__ void k_final(const float* __restrict__ out2, const float* __restrict__ b2,
                        float* out) {
    int idx = blockIdx.x * blockDim.x + threadIdx.x;
    if (idx >= N_GRAPHS * OUT_CH) return;
    out[idx] = out2[idx] + b2[idx & 127];
}

// ---------------- launch ----------------

extern "C" void kernel_launch(void* const* d_in, const int* in_sizes, int n_in,
                              void* d_out, int out_size, void* d_ws, size_t ws_size,
                              hipStream_t stream) {
    const float* x  = (const float*)d_in[0];    // fp32 (validated)
    const int* edge = (const int*)d_in[1];      // int32 (validated)
    const int* src  = edge;
    const int* dst  = edge + N_EDGES;
    const int* ptr  = (const int*)d_in[2];
    const float* W1 = (const float*)d_in[3];
    const float* b1 = (const float*)d_in[4];
    const float* W2 = (const float*)d_in[5];
    const float* b2 = (const float*)d_in[6];
    float* out = (float*)d_out;

    // workspace ~2.3 MB
    char* p = (char*)d_ws;
    auto alloc = [&](size_t bytes) {
        char* r = p; p += (bytes + 255) & ~size_t(255); return r;
    };
    unsigned int* deg  = (unsigned int*)alloc((size_t)N_NODES * 4);
    float* dis      = (float*)alloc((size_t)N_NODES * sizeof(float));
    int*   map1     = (int*)  alloc((size_t)N_NODES * sizeof(int));
    int*   slotnode = (int*)  alloc((size_t)CAPS * sizeof(int));
    int*   list1    = (int*)  alloc((size_t)CAP1 * sizeof(int));
    int*   list2    = (int*)  alloc((size_t)CAP2 * sizeof(int));
    float* h1       = (float*)alloc((size_t)CAPS * HID_CH * sizeof(float));
    float* out2     = (float*)alloc((size_t)N_GRAPHS * OUT_CH * sizeof(float));
    unsigned int* cbm  = (unsigned int*)alloc((size_t)BM_WORDS * 4);
    unsigned int* mbm  = (unsigned int*)alloc((size_t)BM_WORDS * 4);
    unsigned int* ndbm = (unsigned int*)alloc((size_t)BM_WORDS * 4);
    int*   cnt      = (int*)  alloc(256);

    hipLaunchKernelGGL(k_init, dim3(1024), dim3(256), 0, stream,
                       deg, map1, h1, out2, cnt, cbm, mbm, ndbm);
    hipLaunchKernelGGL(k_central, dim3(1), dim3(128), 0, stream,
                       ptr, map1, cbm, ndbm);
    hipLaunchKernelGGL(k_pass1, dim3(SCAN_BLOCKS), dim3(256), 0, stream,
                       src, dst, cbm, map1, list2, cnt);
    hipLaunchKernelGGL(k_node, dim3(512), dim3(256), 0, stream,
                       map1, slotnode, cnt, mbm, ndbm);
    hipLaunchKernelGGL(k_pass2, dim3(SCAN_BLOCKS), dim3(256), 0, stream,
                       src, dst, mbm, list1, cnt, ndbm);
    hipLaunchKernelGGL(k_pass3, dim3(SCAN_BLOCKS), dim3(256), 0, stream,
                       dst, ndbm, deg);
    hipLaunchKernelGGL(k_dis, dim3(512), dim3(256), 0, stream, deg, dis);
    hipLaunchKernelGGL(k_l1_edge, dim3(512), dim3(256), 0, stream,
                       src, dst, x, W1, dis, map1, list1, cnt, h1);
    hipLaunchKernelGGL(k_l1_self, dim3(128), dim3(256), 0, stream,
                       x, W1, b1, dis, slotnode, cnt, h1);
    hipLaunchKernelGGL(k_l2, dim3(64), dim3(256), 0, stream,
                       src, dst, ptr, h1, W2, dis, map1, list2, cnt, out2);
    hipLaunchKernelGGL(k_final, dim3((N_GRAPHS * OUT_CH + 255) / 256), dim3(256), 0, stream,
                       out2, b2, out);
}